// Round 1
// baseline (670.889 us; speedup 1.0000x reference)
//
#include <hip/hip_runtime.h>
#include <stdint.h>

typedef __attribute__((ext_vector_type(8))) short bf16x8;
typedef __attribute__((ext_vector_type(4))) float f32x4;

static constexpr int NN = 50000;
static constexpr int NE = 800000;

// ws layout (element offsets; floats unless noted int)
static constexpr int O_ESUM = 0;            // f32[64]
static constexpr int O_ESQ  = 64;           // f32[64]
static constexpr int O_HSUM = 128;          // f32[64]
static constexpr int O_HSQ  = 192;          // f32[64]
static constexpr int O_ESC  = 256;          // f32[64] edge BN scale
static constexpr int O_ESH  = 320;          // f32[64] edge BN shift
static constexpr int O_HSC  = 384;          // f32[64]
static constexpr int O_HSH  = 448;          // f32[64]
static constexpr int O_CNT  = 512;          // int[NN]
static constexpr int O_ROW  = O_CNT + 50048;   // int[NN+1]
static constexpr int O_CUR  = O_ROW + 50048;   // int[NN]
static constexpr int O_BSUM = O_CUR + 50048;   // int[64]
static constexpr int O_CSR  = O_BSUM + 64;     // int[NE]
static constexpr int O_PHX  = O_CSR + NE;      // f32[NE]
static constexpr int O_AGGH = O_PHX + NE;      // f32[NN*64]
static constexpr int O_YH   = O_AGGH + NN*64;  // f32[NN*64]

static constexpr int OUT_X = NN*64;            // x_new offset in d_out
static constexpr int OUT_M = NN*64 + NN*4;     // m offset in d_out

__device__ __forceinline__ short f2bf(float f){
  uint32_t u = __builtin_bit_cast(uint32_t, f);
  u = (u + 0x7fffu + ((u >> 16) & 1u)) >> 16;
  return (short)u;
}
__device__ __forceinline__ float psi_f(float p){
  return copysignf(__logf(fabsf(p) + 1.0f), p);
}
__device__ __forceinline__ bf16x8 ldrow8(const float* p){
  float4 p0 = *(const float4*)p;
  float4 p1 = *(const float4*)(p + 4);
  bf16x8 a;
  a[0]=f2bf(p0.x); a[1]=f2bf(p0.y); a[2]=f2bf(p0.z); a[3]=f2bf(p0.w);
  a[4]=f2bf(p1.x); a[5]=f2bf(p1.y); a[6]=f2bf(p1.z); a[7]=f2bf(p1.w);
  return a;
}

// ---------------- edge pass 1: y = feat@We1 stats + degree histogram ----------------
__global__ __launch_bounds__(256) void k_e1(
    const float* __restrict__ h, const float* __restrict__ x,
    const int* __restrict__ ei, const int* __restrict__ ej,
    const float* __restrict__ We1, float* __restrict__ wsf, int* __restrict__ wsi)
{
  const int lane = threadIdx.x & 63, wid = threadIdx.x >> 6;
  const int g = lane >> 4, q = lane & 15;

  bf16x8 wf[4][4];
#pragma unroll
  for (int kb=0;kb<4;kb++)
#pragma unroll
    for (int nb=0;nb<4;nb++)
#pragma unroll
      for (int j=0;j<8;j++)
        wf[kb][nb][j] = f2bf(We1[(32*kb + 8*g + j)*64 + 16*nb + q]);

  float wn[4], wd[4];
#pragma unroll
  for (int nb=0;nb<4;nb++){ wn[nb] = We1[128*64 + 16*nb + q]; wd[nb] = We1[129*64 + 16*nb + q]; }

  float ssum[4]={0.f,0.f,0.f,0.f}, ssq[4]={0.f,0.f,0.f,0.f};
  int* cnt = wsi + O_CNT;

  const int gw = blockIdx.x*4 + wid, nw = gridDim.x*4;
  for (int t = gw; t < NE/16; t += nw){
    const int eb = t*16;
    const int iq = ei[eb + q], jq = ej[eb + q];
    const float4 xi = *(const float4*)(x + 4*iq);
    const float4 xj = *(const float4*)(x + 4*jq);
    const float dx=xi.x-xj.x, dy=xi.y-xj.y, dz=xi.z-xj.z, dw=xi.w-xj.w;
    const float nrm = psi_f(dx*dx - dy*dy - dz*dz - dw*dw);
    const float dot = psi_f(xi.x*xj.x - xi.y*xj.y - xi.z*xj.z - xi.w*xj.w);

    bf16x8 a[4];
    const float* hi = h + (size_t)iq*64;
    const float* hj = h + (size_t)jq*64;
    a[0] = ldrow8(hi + 8*g);      a[1] = ldrow8(hi + 32 + 8*g);
    a[2] = ldrow8(hj + 8*g);      a[3] = ldrow8(hj + 32 + 8*g);

    float nr[4], dr[4];
#pragma unroll
    for (int r=0;r<4;r++){ nr[r] = __shfl(nrm, 4*g+r, 64); dr[r] = __shfl(dot, 4*g+r, 64); }

    f32x4 acc[4];
#pragma unroll
    for (int nb=0;nb<4;nb++)
#pragma unroll
      for (int r=0;r<4;r++)
        acc[nb][r] = nr[r]*wn[nb] + dr[r]*wd[nb];

#pragma unroll
    for (int kb=0;kb<4;kb++)
#pragma unroll
      for (int nb=0;nb<4;nb++)
        acc[nb] = __builtin_amdgcn_mfma_f32_16x16x32_bf16(a[kb], wf[kb][nb], acc[nb], 0,0,0);

#pragma unroll
    for (int nb=0;nb<4;nb++)
#pragma unroll
      for (int r=0;r<4;r++){ float v = acc[nb][r]; ssum[nb] += v; ssq[nb] += v*v; }

    if (lane < 16) atomicAdd(cnt + iq, 1);
  }

#pragma unroll
  for (int nb=0;nb<4;nb++){
    float s = ssum[nb], z = ssq[nb];
    s += __shfl_xor(s,16,64); s += __shfl_xor(s,32,64);
    z += __shfl_xor(z,16,64); z += __shfl_xor(z,32,64);
    if (lane < 16){
      atomicAdd(wsf + O_ESUM + 16*nb + lane, s);
      atomicAdd(wsf + O_ESQ  + 16*nb + lane, z);
    }
  }
}

// ---------------- BN stats -> scale/shift ----------------
__global__ void k_stats(const float* __restrict__ sum, const float* __restrict__ sq,
                        const float* __restrict__ gam, const float* __restrict__ bet,
                        float* __restrict__ scale, float* __restrict__ shift, float invc){
  int t = threadIdx.x;
  float mu = sum[t]*invc;
  float var = sq[t]*invc - mu*mu;
  float rstd = rsqrtf(var + 1e-5f);
  float sc = gam[t]*rstd;
  scale[t] = sc;
  shift[t] = bet[t] - mu*sc;
}

// ---------------- CSR build: scan + scatter ----------------
__global__ __launch_bounds__(1024) void k_scan_a(const int* __restrict__ cnt, int* __restrict__ row1,
                                                 int* __restrict__ bsum, int n){
  int v = blockIdx.x*1024 + threadIdx.x;
  int x = (v < n) ? cnt[v] : 0;
  const int lane = threadIdx.x & 63, wid = threadIdx.x >> 6;
#pragma unroll
  for (int d=1; d<64; d<<=1){ int y = __shfl_up(x, d, 64); if (lane >= d) x += y; }
  __shared__ int ws[16];
  if (lane == 63) ws[wid] = x;
  __syncthreads();
  if (wid == 0){
    int s = (lane < 16) ? ws[lane] : 0;
#pragma unroll
    for (int d=1; d<16; d<<=1){ int y = __shfl_up(s, d, 64); if (lane >= d) s += y; }
    if (lane < 16) ws[lane] = s;
  }
  __syncthreads();
  if (wid > 0) x += ws[wid-1];
  if (v < n) row1[v] = x;
  if (threadIdx.x == 1023) bsum[blockIdx.x] = x;
}

__global__ void k_scan_b(int* __restrict__ bsum, int nb){
  int t = threadIdx.x;
  int s = (t < nb) ? bsum[t] : 0;
#pragma unroll
  for (int d=1; d<64; d<<=1){ int y = __shfl_up(s, d, 64); if (t >= d) s += y; }
  if (t < nb) bsum[t] = s;
}

__global__ __launch_bounds__(1024) void k_scan_c(const int* __restrict__ cnt, int* __restrict__ row,
                                                 int* __restrict__ cur, const int* __restrict__ bsum, int n){
  int v = blockIdx.x*1024 + threadIdx.x;
  if (v == 0) row[0] = 0;
  if (v < n){
    int off = (blockIdx.x > 0) ? bsum[blockIdx.x-1] : 0;
    int incl = row[v+1] + off;
    row[v+1] = incl;
    cur[v] = incl - cnt[v];
  }
}

__global__ __launch_bounds__(256) void k_scatter(const int* __restrict__ ei, int* __restrict__ cur,
                                                 int* __restrict__ csr){
  int e = blockIdx.x*256 + threadIdx.x;
  if (e < NE){ int v = ei[e]; int p = atomicAdd(cur + v, 1); csr[p] = e; }
}

// ---------------- edge pass 2: full fused edge chain ----------------
__global__ __launch_bounds__(256) void k_e2(
    const float* __restrict__ h, const float* __restrict__ x,
    const int* __restrict__ ei, const int* __restrict__ ej,
    const float* __restrict__ We1, const float* __restrict__ We2, const float* __restrict__ be2,
    const float* __restrict__ Wm, const float* __restrict__ bm,
    const float* __restrict__ Wx1, const float* __restrict__ bx1, const float* __restrict__ Wx2,
    const float* __restrict__ wsf, float* __restrict__ outm, float* __restrict__ phx)
{
  __shared__ uint4 sW[2048];                 // [0,1024) We1 | [1024,1536) We2 | [1536,2048) Wx1
  __shared__ __align__(16) ushort sT[4][1024];

  const int tid = threadIdx.x;
  const int lane = tid & 63, wid = tid >> 6;
  const int g = lane >> 4, q = lane & 15;

  for (int idx = tid; idx < 2048; idx += 256){
    const float* Wsrc; int base;
    if (idx < 1024){ Wsrc = We1; base = idx; }
    else if (idx < 1536){ Wsrc = We2; base = idx - 1024; }
    else { Wsrc = Wx1; base = idx - 1536; }
    const int c = base >> 6, L = base & 63;
    const int kb = c >> 2, nb = c & 3;
    const int Lg = L >> 4, Ln = L & 15;
    uint32_t w[8];
#pragma unroll
    for (int j=0;j<8;j++)
      w[j] = (uint32_t)(uint16_t)f2bf(Wsrc[(32*kb + 8*Lg + j)*64 + 16*nb + Ln]);
    uint4 u;
    u.x = w[0] | (w[1]<<16); u.y = w[2] | (w[3]<<16);
    u.z = w[4] | (w[5]<<16); u.w = w[6] | (w[7]<<16);
    sW[idx] = u;
  }
  __syncthreads();

  float escale[4], eshift[4], vbe2[4], vbx1[4], vwm[4], vwx2[4], wn[4], wd[4];
#pragma unroll
  for (int nb=0;nb<4;nb++){
    const int c = 16*nb + q;
    escale[nb] = wsf[O_ESC + c]; eshift[nb] = wsf[O_ESH + c];
    vbe2[nb] = be2[c]; vbx1[nb] = bx1[c];
    vwm[nb] = Wm[c];  vwx2[nb] = Wx2[c];
    wn[nb] = We1[128*64 + c]; wd[nb] = We1[129*64 + c];
  }
  const float bmv = bm[0];
  ushort* tb = sT[wid];

  const int gw = blockIdx.x*4 + wid, nw = gridDim.x*4;
  for (int t = gw; t < NE/16; t += nw){
    const int eb = t*16;
    const int iq = ei[eb + q], jq = ej[eb + q];
    const float4 xi = *(const float4*)(x + 4*iq);
    const float4 xj = *(const float4*)(x + 4*jq);
    const float dx=xi.x-xj.x, dy=xi.y-xj.y, dz=xi.z-xj.z, dw=xi.w-xj.w;
    const float nrm = psi_f(dx*dx - dy*dy - dz*dz - dw*dw);
    const float dot = psi_f(xi.x*xj.x - xi.y*xj.y - xi.z*xj.z - xi.w*xj.w);

    bf16x8 a[4];
    const float* hi = h + (size_t)iq*64;
    const float* hj = h + (size_t)jq*64;
    a[0] = ldrow8(hi + 8*g);      a[1] = ldrow8(hi + 32 + 8*g);
    a[2] = ldrow8(hj + 8*g);      a[3] = ldrow8(hj + 32 + 8*g);

    float nr[4], dr[4];
#pragma unroll
    for (int r=0;r<4;r++){ nr[r] = __shfl(nrm, 4*g+r, 64); dr[r] = __shfl(dot, 4*g+r, 64); }

    f32x4 acc[4];
#pragma unroll
    for (int nb=0;nb<4;nb++)
#pragma unroll
      for (int r=0;r<4;r++)
        acc[nb][r] = nr[r]*wn[nb] + dr[r]*wd[nb];
#pragma unroll
    for (int kb=0;kb<4;kb++)
#pragma unroll
      for (int nb=0;nb<4;nb++)
        acc[nb] = __builtin_amdgcn_mfma_f32_16x16x32_bf16(
            a[kb], __builtin_bit_cast(bf16x8, sW[(kb*4+nb)*64 + lane]), acc[nb], 0,0,0);

    float o1[4][4];
#pragma unroll
    for (int nb=0;nb<4;nb++)
#pragma unroll
      for (int r=0;r<4;r++)
        o1[nb][r] = fmaxf(acc[nb][r]*escale[nb] + eshift[nb], 0.f);

    // transpose bounce 1 (D-layout -> A-layout), XOR-swizzled to dodge bank conflicts
    asm volatile("s_waitcnt lgkmcnt(0)" ::: "memory");
#pragma unroll
    for (int nb=0;nb<4;nb++)
#pragma unroll
      for (int r=0;r<4;r++){
        const int mr = 4*g + r;
        tb[mr*64 + ((16*nb + q) ^ ((mr&7)<<3))] = (ushort)f2bf(o1[nb][r]);
      }
    asm volatile("s_waitcnt lgkmcnt(0)" ::: "memory");
    bf16x8 a2[2];
#pragma unroll
    for (int kb=0;kb<2;kb++){
      const int k0 = 32*kb + 8*g;
      uint4 uv = *(const uint4*)(tb + q*64 + (k0 ^ ((q&7)<<3)));
      a2[kb] = __builtin_bit_cast(bf16x8, uv);
    }

    f32x4 acc2[4];
#pragma unroll
    for (int nb=0;nb<4;nb++){ acc2[nb][0]=vbe2[nb]; acc2[nb][1]=vbe2[nb]; acc2[nb][2]=vbe2[nb]; acc2[nb][3]=vbe2[nb]; }
#pragma unroll
    for (int kb=0;kb<2;kb++)
#pragma unroll
      for (int nb=0;nb<4;nb++)
        acc2[nb] = __builtin_amdgcn_mfma_f32_16x16x32_bf16(
            a2[kb], __builtin_bit_cast(bf16x8, sW[1024 + (kb*4+nb)*64 + lane]), acc2[nb], 0,0,0);

    float o2[4][4];
#pragma unroll
    for (int nb=0;nb<4;nb++)
#pragma unroll
      for (int r=0;r<4;r++)
        o2[nb][r] = fmaxf(acc2[nb][r], 0.f);

    float gate[4];
#pragma unroll
    for (int r=0;r<4;r++){
      float s = o2[0][r]*vwm[0] + o2[1][r]*vwm[1] + o2[2][r]*vwm[2] + o2[3][r]*vwm[3];
      s += __shfl_xor(s,1,64); s += __shfl_xor(s,2,64);
      s += __shfl_xor(s,4,64); s += __shfl_xor(s,8,64);
      gate[r] = 1.f/(1.f + __expf(-(s + bmv)));
    }

    float mv[4][4];
#pragma unroll
    for (int nb=0;nb<4;nb++)
#pragma unroll
      for (int r=0;r<4;r++){
        mv[nb][r] = o2[nb][r]*gate[r];
        outm[(size_t)(eb + 4*g + r)*64 + 16*nb + q] = mv[nb][r];
      }

    // transpose bounce 2 (m -> A-layout)
    asm volatile("s_waitcnt lgkmcnt(0)" ::: "memory");
#pragma unroll
    for (int nb=0;nb<4;nb++)
#pragma unroll
      for (int r=0;r<4;r++){
        const int mr = 4*g + r;
        tb[mr*64 + ((16*nb + q) ^ ((mr&7)<<3))] = (ushort)f2bf(mv[nb][r]);
      }
    asm volatile("s_waitcnt lgkmcnt(0)" ::: "memory");
    bf16x8 a3[2];
#pragma unroll
    for (int kb=0;kb<2;kb++){
      const int k0 = 32*kb + 8*g;
      uint4 uv = *(const uint4*)(tb + q*64 + (k0 ^ ((q&7)<<3)));
      a3[kb] = __builtin_bit_cast(bf16x8, uv);
    }

    f32x4 acc3[4];
#pragma unroll
    for (int nb=0;nb<4;nb++){ acc3[nb][0]=vbx1[nb]; acc3[nb][1]=vbx1[nb]; acc3[nb][2]=vbx1[nb]; acc3[nb][3]=vbx1[nb]; }
#pragma unroll
    for (int kb=0;kb<2;kb++)
#pragma unroll
      for (int nb=0;nb<4;nb++)
        acc3[nb] = __builtin_amdgcn_mfma_f32_16x16x32_bf16(
            a3[kb], __builtin_bit_cast(bf16x8, sW[1536 + (kb*4+nb)*64 + lane]), acc3[nb], 0,0,0);

    float pd[4];
#pragma unroll
    for (int r=0;r<4;r++){
      float s = fmaxf(acc3[0][r],0.f)*vwx2[0] + fmaxf(acc3[1][r],0.f)*vwx2[1]
              + fmaxf(acc3[2][r],0.f)*vwx2[2] + fmaxf(acc3[3][r],0.f)*vwx2[3];
      s += __shfl_xor(s,1,64); s += __shfl_xor(s,2,64);
      s += __shfl_xor(s,4,64); s += __shfl_xor(s,8,64);
      pd[r] = s;
    }
    if (q == 0){
#pragma unroll
      for (int r=0;r<4;r++) phx[eb + 4*g + r] = pd[r];
    }
  }
}

// ---------------- per-node aggregation: agg_h and x_new ----------------
__global__ __launch_bounds__(256) void k_agg(
    const float* __restrict__ x, const int* __restrict__ ej,
    const int* __restrict__ row, const int* __restrict__ csr,
    const float* __restrict__ m, const float* __restrict__ phx,
    float* __restrict__ aggh, float* __restrict__ out)
{
  const int lane = threadIdx.x & 63, wid = threadIdx.x >> 6;
  const int gw = blockIdx.x*4 + wid, nw = gridDim.x*4;
  for (int v = gw; v < NN; v += nw){
    const int s = row[v], e1 = row[v+1];
    float ah = 0.f;
    float xv = (lane < 4) ? x[4*v + lane] : 0.f;
    float ax = 0.f;
    for (int p = s; p < e1; p++){
      const int e = csr[p];
      ah += m[(size_t)e*64 + lane];
      if (lane < 4){
        const int j = ej[e];
        float tr = (xv - x[4*j + lane]) * phx[e];
        tr = fminf(fmaxf(tr, -100.f), 100.f);
        ax += tr;
      }
    }
    aggh[(size_t)v*64 + lane] = ah;
    if (lane < 4){
      const float deg = (float)(e1 - s);
      out[OUT_X + 4*v + lane] = xv + ax / fmaxf(deg, 1.f);
    }
  }
}

// ---------------- node pass 1: y_h = hin@Wh1 (bias dropped: BN absorbs it) + stats ----------------
__global__ __launch_bounds__(256) void k_h1(
    const float* __restrict__ h, const float* __restrict__ aggh, const float* __restrict__ attr,
    const float* __restrict__ Wh1, float* __restrict__ yh, float* __restrict__ wsf)
{
  const int lane = threadIdx.x & 63, wid = threadIdx.x >> 6;
  const int g = lane >> 4, q = lane & 15;

  bf16x8 wf[4][4];
#pragma unroll
  for (int kb=0;kb<4;kb++)
#pragma unroll
    for (int nb=0;nb<4;nb++)
#pragma unroll
      for (int j=0;j<8;j++)
        wf[kb][nb][j] = f2bf(Wh1[(32*kb + 8*g + j)*64 + 16*nb + q]);
  float wa[8][4];
#pragma unroll
  for (int a8=0;a8<8;a8++)
#pragma unroll
    for (int nb=0;nb<4;nb++)
      wa[a8][nb] = Wh1[(128+a8)*64 + 16*nb + q];

  float ssum[4]={0.f,0.f,0.f,0.f}, ssq[4]={0.f,0.f,0.f,0.f};
  const int gw = blockIdx.x*4 + wid, nw = gridDim.x*4;
  for (int t = gw; t < NN/16; t += nw){
    const int rb = t*16;
    bf16x8 a[4];
    const float* hp = h    + (size_t)(rb+q)*64;
    const float* ap = aggh + (size_t)(rb+q)*64;
    a[0]=ldrow8(hp + 8*g); a[1]=ldrow8(hp + 32 + 8*g);
    a[2]=ldrow8(ap + 8*g); a[3]=ldrow8(ap + 32 + 8*g);

    float at[4][8];
#pragma unroll
    for (int r=0;r<4;r++){
      const float* pp = attr + (size_t)(rb + 4*g + r)*8;
      float4 p0 = *(const float4*)pp; float4 p1 = *(const float4*)(pp + 4);
      at[r][0]=p0.x; at[r][1]=p0.y; at[r][2]=p0.z; at[r][3]=p0.w;
      at[r][4]=p1.x; at[r][5]=p1.y; at[r][6]=p1.z; at[r][7]=p1.w;
    }
    f32x4 acc[4];
#pragma unroll
    for (int nb=0;nb<4;nb++)
#pragma unroll
      for (int r=0;r<4;r++){
        float ci = 0.f;
#pragma unroll
        for (int a8=0;a8<8;a8++) ci += at[r][a8]*wa[a8][nb];
        acc[nb][r] = ci;
      }
#pragma unroll
    for (int kb=0;kb<4;kb++)
#pragma unroll
      for (int nb=0;nb<4;nb++)
        acc[nb] = __builtin_amdgcn_mfma_f32_16x16x32_bf16(a[kb], wf[kb][nb], acc[nb], 0,0,0);

#pragma unroll
    for (int nb=0;nb<4;nb++)
#pragma unroll
      for (int r=0;r<4;r++){
        float v = acc[nb][r];
        yh[(size_t)(rb + 4*g + r)*64 + 16*nb + q] = v;
        ssum[nb] += v; ssq[nb] += v*v;
      }
  }
#pragma unroll
  for (int nb=0;nb<4;nb++){
    float s = ssum[nb], z = ssq[nb];
    s += __shfl_xor(s,16,64); s += __shfl_xor(s,32,64);
    z += __shfl_xor(z,16,64); z += __shfl_xor(z,32,64);
    if (lane < 16){
      atomicAdd(wsf + O_HSUM + 16*nb + lane, s);
      atomicAdd(wsf + O_HSQ  + 16*nb + lane, z);
    }
  }
}

// ---------------- node pass 2: h_new = h + relu(BN(y_h))@Wh2 + b_h2 ----------------
__global__ __launch_bounds__(256) void k_h2(
    const float* __restrict__ h, const float* __restrict__ yh,
    const float* __restrict__ Wh2, const float* __restrict__ bh2,
    const float* __restrict__ wsf, float* __restrict__ out)
{
  const int lane = threadIdx.x & 63, wid = threadIdx.x >> 6;
  const int g = lane >> 4, q = lane & 15;

  bf16x8 wf[2][4];
#pragma unroll
  for (int kb=0;kb<2;kb++)
#pragma unroll
    for (int nb=0;nb<4;nb++)
#pragma unroll
      for (int j=0;j<8;j++)
        wf[kb][nb][j] = f2bf(Wh2[(32*kb + 8*g + j)*64 + 16*nb + q]);

  float sc[2][8], sh[2][8];
#pragma unroll
  for (int kb=0;kb<2;kb++)
#pragma unroll
    for (int j=0;j<8;j++){
      const int k = 32*kb + 8*g + j;
      sc[kb][j] = wsf[O_HSC + k]; sh[kb][j] = wsf[O_HSH + k];
    }
  float vb[4];
#pragma unroll
  for (int nb=0;nb<4;nb++) vb[nb] = bh2[16*nb + q];

  const int gw = blockIdx.x*4 + wid, nw = gridDim.x*4;
  for (int t = gw; t < NN/16; t += nw){
    const int rb = t*16;
    const float* yp = yh + (size_t)(rb+q)*64;
    bf16x8 a[2];
#pragma unroll
    for (int kb=0;kb<2;kb++){
      float4 p0 = *(const float4*)(yp + 32*kb + 8*g);
      float4 p1 = *(const float4*)(yp + 32*kb + 8*g + 4);
      float v[8] = {p0.x,p0.y,p0.z,p0.w,p1.x,p1.y,p1.z,p1.w};
#pragma unroll
      for (int j=0;j<8;j++)
        a[kb][j] = f2bf(fmaxf(v[j]*sc[kb][j] + sh[kb][j], 0.f));
    }
    f32x4 acc[4];
#pragma unroll
    for (int nb=0;nb<4;nb++){ acc[nb][0]=vb[nb]; acc[nb][1]=vb[nb]; acc[nb][2]=vb[nb]; acc[nb][3]=vb[nb]; }
#pragma unroll
    for (int kb=0;kb<2;kb++)
#pragma unroll
      for (int nb=0;nb<4;nb++)
        acc[nb] = __builtin_amdgcn_mfma_f32_16x16x32_bf16(a[kb], wf[kb][nb], acc[nb], 0,0,0);

#pragma unroll
    for (int nb=0;nb<4;nb++)
#pragma unroll
      for (int r=0;r<4;r++){
        const size_t idx = (size_t)(rb + 4*g + r)*64 + 16*nb + q;
        out[idx] = h[idx] + acc[nb][r];
      }
  }
}

extern "C" void kernel_launch(void* const* d_in, const int* in_sizes, int n_in,
                              void* d_out, int out_size, void* d_ws, size_t ws_size,
                              hipStream_t stream){
  const float* h    = (const float*)d_in[0];
  const float* x    = (const float*)d_in[1];
  const int*   ei   = (const int*)d_in[2];
  const int*   ej   = (const int*)d_in[3];
  const float* attr = (const float*)d_in[4];
  const float* We1  = (const float*)d_in[5];
  const float* ge   = (const float*)d_in[6];
  const float* be   = (const float*)d_in[7];
  const float* We2  = (const float*)d_in[8];
  const float* be2  = (const float*)d_in[9];
  const float* Wm   = (const float*)d_in[10];
  const float* bm   = (const float*)d_in[11];
  const float* Wx1  = (const float*)d_in[12];
  const float* bx1  = (const float*)d_in[13];
  const float* Wx2  = (const float*)d_in[14];
  const float* Wh1  = (const float*)d_in[15];
  // d_in[16] = b_h1 : absorbed by batchnorm, unused
  const float* gh   = (const float*)d_in[17];
  const float* bh   = (const float*)d_in[18];
  const float* Wh2  = (const float*)d_in[19];
  const float* bh2  = (const float*)d_in[20];

  float* out = (float*)d_out;
  float* wsf = (float*)d_ws;
  int*   wsi = (int*)d_ws;

  hipMemsetAsync(wsf + O_ESUM, 0, 256*sizeof(float), stream);   // all 4 stat blocks
  hipMemsetAsync(wsi + O_CNT, 0, NN*sizeof(int), stream);

  k_e1<<<512,256,0,stream>>>(h, x, ei, ej, We1, wsf, wsi);
  k_stats<<<1,64,0,stream>>>(wsf+O_ESUM, wsf+O_ESQ, ge, be, wsf+O_ESC, wsf+O_ESH, 1.0f/(float)NE);
  k_scan_a<<<49,1024,0,stream>>>(wsi+O_CNT, wsi+O_ROW+1, wsi+O_BSUM, NN);
  k_scan_b<<<1,64,0,stream>>>(wsi+O_BSUM, 49);
  k_scan_c<<<49,1024,0,stream>>>(wsi+O_CNT, wsi+O_ROW, wsi+O_CUR, wsi+O_BSUM, NN);
  k_scatter<<<(NE+255)/256,256,0,stream>>>(ei, wsi+O_CUR, wsi+O_CSR);
  k_e2<<<1024,256,0,stream>>>(h, x, ei, ej, We1, We2, be2, Wm, bm, Wx1, bx1, Wx2,
                              wsf, out + OUT_M, wsf + O_PHX);
  k_agg<<<512,256,0,stream>>>(x, ej, wsi+O_ROW, wsi+O_CSR, out + OUT_M, wsf + O_PHX,
                              wsf + O_AGGH, out);
  k_h1<<<256,256,0,stream>>>(h, wsf + O_AGGH, attr, Wh1, wsf + O_YH, wsf);
  k_stats<<<1,64,0,stream>>>(wsf+O_HSUM, wsf+O_HSQ, gh, bh, wsf+O_HSC, wsf+O_HSH, 1.0f/(float)NN);
  k_h2<<<256,256,0,stream>>>(h, wsf + O_YH, Wh2, bh2, wsf, out);
}

// Round 2
// 403.030 us; speedup vs baseline: 1.6646x; 1.6646x over previous
//
#include <hip/hip_runtime.h>
#include <stdint.h>

typedef __attribute__((ext_vector_type(8))) short bf16x8;
typedef __attribute__((ext_vector_type(4))) float f32x4;

static constexpr int NN = 50000;
static constexpr int NE = 800000;

// ws layout (element offsets; floats unless noted int)
static constexpr int O_ESUM = 0;            // f32[64]
static constexpr int O_ESQ  = 64;           // f32[64]
static constexpr int O_HSUM = 128;          // f32[64]
static constexpr int O_HSQ  = 192;          // f32[64]
static constexpr int O_ESC  = 256;          // f32[64] edge BN scale
static constexpr int O_ESH  = 320;          // f32[64] edge BN shift
static constexpr int O_HSC  = 384;          // f32[64]
static constexpr int O_HSH  = 448;          // f32[64]
static constexpr int O_CNT  = 512;          // int[NN]
static constexpr int O_ROW  = O_CNT + 50048;   // int[NN+1]
static constexpr int O_CUR  = O_ROW + 50048;   // int[NN]
static constexpr int O_BSUM = O_CUR + 50048;   // int[64]
static constexpr int O_CSR  = O_BSUM + 64;     // int[NE]
static constexpr int O_PHX  = O_CSR + NE;      // f32[NE]
static constexpr int O_AGGH = O_PHX + NE;      // f32[NN*64]
static constexpr int O_YH   = O_AGGH + NN*64;  // f32[NN*64]

static constexpr int OUT_X = NN*64;            // x_new offset in d_out
static constexpr int OUT_M = NN*64 + NN*4;     // m offset in d_out

__device__ __forceinline__ short f2bf(float f){
  uint32_t u = __builtin_bit_cast(uint32_t, f);
  u = (u + 0x7fffu + ((u >> 16) & 1u)) >> 16;
  return (short)u;
}
__device__ __forceinline__ float psi_f(float p){
  return copysignf(__logf(fabsf(p) + 1.0f), p);
}
__device__ __forceinline__ bf16x8 ldrow8(const float* p){
  float4 p0 = *(const float4*)p;
  float4 p1 = *(const float4*)(p + 4);
  bf16x8 a;
  a[0]=f2bf(p0.x); a[1]=f2bf(p0.y); a[2]=f2bf(p0.z); a[3]=f2bf(p0.w);
  a[4]=f2bf(p1.x); a[5]=f2bf(p1.y); a[6]=f2bf(p1.z); a[7]=f2bf(p1.w);
  return a;
}

// ---------------- edge pass 1: y = feat@We1 stats + degree histogram ----------------
__global__ __launch_bounds__(256) void k_e1(
    const float* __restrict__ h, const float* __restrict__ x,
    const int* __restrict__ ei, const int* __restrict__ ej,
    const float* __restrict__ We1, float* __restrict__ wsf, int* __restrict__ wsi)
{
  const int lane = threadIdx.x & 63, wid = threadIdx.x >> 6;
  const int g = lane >> 4, q = lane & 15;

  bf16x8 wf[4][4];
#pragma unroll
  for (int kb=0;kb<4;kb++)
#pragma unroll
    for (int nb=0;nb<4;nb++)
#pragma unroll
      for (int j=0;j<8;j++)
        wf[kb][nb][j] = f2bf(We1[(32*kb + 8*g + j)*64 + 16*nb + q]);

  float wn[4], wd[4];
#pragma unroll
  for (int nb=0;nb<4;nb++){ wn[nb] = We1[128*64 + 16*nb + q]; wd[nb] = We1[129*64 + 16*nb + q]; }

  float ssum[4]={0.f,0.f,0.f,0.f}, ssq[4]={0.f,0.f,0.f,0.f};
  int* cnt = wsi + O_CNT;

  const int gw = blockIdx.x*4 + wid, nw = gridDim.x*4;
  for (int t = gw; t < NE/16; t += nw){
    const int eb = t*16;
    const int iq = ei[eb + q], jq = ej[eb + q];
    const float4 xi = *(const float4*)(x + 4*iq);
    const float4 xj = *(const float4*)(x + 4*jq);
    const float dx=xi.x-xj.x, dy=xi.y-xj.y, dz=xi.z-xj.z, dw=xi.w-xj.w;
    const float nrm = psi_f(dx*dx - dy*dy - dz*dz - dw*dw);
    const float dot = psi_f(xi.x*xj.x - xi.y*xj.y - xi.z*xj.z - xi.w*xj.w);

    bf16x8 a[4];
    const float* hi = h + (size_t)iq*64;
    const float* hj = h + (size_t)jq*64;
    a[0] = ldrow8(hi + 8*g);      a[1] = ldrow8(hi + 32 + 8*g);
    a[2] = ldrow8(hj + 8*g);      a[3] = ldrow8(hj + 32 + 8*g);

    float nr[4], dr[4];
#pragma unroll
    for (int r=0;r<4;r++){ nr[r] = __shfl(nrm, 4*g+r, 64); dr[r] = __shfl(dot, 4*g+r, 64); }

    f32x4 acc[4];
#pragma unroll
    for (int nb=0;nb<4;nb++)
#pragma unroll
      for (int r=0;r<4;r++)
        acc[nb][r] = nr[r]*wn[nb] + dr[r]*wd[nb];

#pragma unroll
    for (int kb=0;kb<4;kb++)
#pragma unroll
      for (int nb=0;nb<4;nb++)
        acc[nb] = __builtin_amdgcn_mfma_f32_16x16x32_bf16(a[kb], wf[kb][nb], acc[nb], 0,0,0);

#pragma unroll
    for (int nb=0;nb<4;nb++)
#pragma unroll
      for (int r=0;r<4;r++){ float v = acc[nb][r]; ssum[nb] += v; ssq[nb] += v*v; }

    if (lane < 16) atomicAdd(cnt + iq, 1);
  }

#pragma unroll
  for (int nb=0;nb<4;nb++){
    float s = ssum[nb], z = ssq[nb];
    s += __shfl_xor(s,16,64); s += __shfl_xor(s,32,64);
    z += __shfl_xor(z,16,64); z += __shfl_xor(z,32,64);
    if (lane < 16){
      atomicAdd(wsf + O_ESUM + 16*nb + lane, s);
      atomicAdd(wsf + O_ESQ  + 16*nb + lane, z);
    }
  }
}

// ---------------- BN stats -> scale/shift ----------------
__global__ void k_stats(const float* __restrict__ sum, const float* __restrict__ sq,
                        const float* __restrict__ gam, const float* __restrict__ bet,
                        float* __restrict__ scale, float* __restrict__ shift, float invc){
  int t = threadIdx.x;
  float mu = sum[t]*invc;
  float var = sq[t]*invc - mu*mu;
  float rstd = rsqrtf(var + 1e-5f);
  float sc = gam[t]*rstd;
  scale[t] = sc;
  shift[t] = bet[t] - mu*sc;
}

// ---------------- CSR build: scan + scatter ----------------
__global__ __launch_bounds__(1024) void k_scan_a(const int* __restrict__ cnt, int* __restrict__ row1,
                                                 int* __restrict__ bsum, int n){
  int v = blockIdx.x*1024 + threadIdx.x;
  int x = (v < n) ? cnt[v] : 0;
  const int lane = threadIdx.x & 63, wid = threadIdx.x >> 6;
#pragma unroll
  for (int d=1; d<64; d<<=1){ int y = __shfl_up(x, d, 64); if (lane >= d) x += y; }
  __shared__ int ws[16];
  if (lane == 63) ws[wid] = x;
  __syncthreads();
  if (wid == 0){
    int s = (lane < 16) ? ws[lane] : 0;
#pragma unroll
    for (int d=1; d<16; d<<=1){ int y = __shfl_up(s, d, 64); if (lane >= d) s += y; }
    if (lane < 16) ws[lane] = s;
  }
  __syncthreads();
  if (wid > 0) x += ws[wid-1];
  if (v < n) row1[v] = x;
  if (threadIdx.x == 1023) bsum[blockIdx.x] = x;
}

__global__ void k_scan_b(int* __restrict__ bsum, int nb){
  int t = threadIdx.x;
  int s = (t < nb) ? bsum[t] : 0;
#pragma unroll
  for (int d=1; d<64; d<<=1){ int y = __shfl_up(s, d, 64); if (t >= d) s += y; }
  if (t < nb) bsum[t] = s;
}

__global__ __launch_bounds__(1024) void k_scan_c(const int* __restrict__ cnt, int* __restrict__ row,
                                                 int* __restrict__ cur, const int* __restrict__ bsum, int n){
  int v = blockIdx.x*1024 + threadIdx.x;
  if (v == 0) row[0] = 0;
  if (v < n){
    int off = (blockIdx.x > 0) ? bsum[blockIdx.x-1] : 0;
    int incl = row[v+1] + off;
    row[v+1] = incl;
    cur[v] = incl - cnt[v];
  }
}

__global__ __launch_bounds__(256) void k_scatter(const int* __restrict__ ei, int* __restrict__ cur,
                                                 int* __restrict__ csr){
  int e = blockIdx.x*256 + threadIdx.x;
  if (e < NE){ int v = ei[e]; int p = atomicAdd(cur + v, 1); csr[p] = e; }
}

// ---------------- edge pass 2: full fused edge chain ----------------
__global__ __launch_bounds__(256) void k_e2(
    const float* __restrict__ h, const float* __restrict__ x,
    const int* __restrict__ ei, const int* __restrict__ ej,
    const float* __restrict__ We1, const float* __restrict__ We2, const float* __restrict__ be2,
    const float* __restrict__ Wm, const float* __restrict__ bm,
    const float* __restrict__ Wx1, const float* __restrict__ bx1, const float* __restrict__ Wx2,
    const float* __restrict__ wsf, float* __restrict__ outm, float* __restrict__ phx)
{
  __shared__ uint4 sW[2048];                 // [0,1024) We1 | [1024,1536) We2 | [1536,2048) Wx1
  __shared__ __align__(16) ushort sT[4][1024];

  const int tid = threadIdx.x;
  const int lane = tid & 63, wid = tid >> 6;
  const int g = lane >> 4, q = lane & 15;

  for (int idx = tid; idx < 2048; idx += 256){
    const float* Wsrc; int base;
    if (idx < 1024){ Wsrc = We1; base = idx; }
    else if (idx < 1536){ Wsrc = We2; base = idx - 1024; }
    else { Wsrc = Wx1; base = idx - 1536; }
    const int c = base >> 6, L = base & 63;
    const int kb = c >> 2, nb = c & 3;
    const int Lg = L >> 4, Ln = L & 15;
    uint32_t w[8];
#pragma unroll
    for (int j=0;j<8;j++)
      w[j] = (uint32_t)(uint16_t)f2bf(Wsrc[(32*kb + 8*Lg + j)*64 + 16*nb + Ln]);
    uint4 u;
    u.x = w[0] | (w[1]<<16); u.y = w[2] | (w[3]<<16);
    u.z = w[4] | (w[5]<<16); u.w = w[6] | (w[7]<<16);
    sW[idx] = u;
  }
  __syncthreads();

  float escale[4], eshift[4], vbe2[4], vbx1[4], vwm[4], vwx2[4], wn[4], wd[4];
#pragma unroll
  for (int nb=0;nb<4;nb++){
    const int c = 16*nb + q;
    escale[nb] = wsf[O_ESC + c]; eshift[nb] = wsf[O_ESH + c];
    vbe2[nb] = be2[c]; vbx1[nb] = bx1[c];
    vwm[nb] = Wm[c];  vwx2[nb] = Wx2[c];
    wn[nb] = We1[128*64 + c]; wd[nb] = We1[129*64 + c];
  }
  const float bmv = bm[0];
  ushort* tb = sT[wid];

  const int gw = blockIdx.x*4 + wid, nw = gridDim.x*4;
  for (int t = gw; t < NE/16; t += nw){
    const int eb = t*16;
    const int iq = ei[eb + q], jq = ej[eb + q];
    const float4 xi = *(const float4*)(x + 4*iq);
    const float4 xj = *(const float4*)(x + 4*jq);
    const float dx=xi.x-xj.x, dy=xi.y-xj.y, dz=xi.z-xj.z, dw=xi.w-xj.w;
    const float nrm = psi_f(dx*dx - dy*dy - dz*dz - dw*dw);
    const float dot = psi_f(xi.x*xj.x - xi.y*xj.y - xi.z*xj.z - xi.w*xj.w);

    bf16x8 a[4];
    const float* hi = h + (size_t)iq*64;
    const float* hj = h + (size_t)jq*64;
    a[0] = ldrow8(hi + 8*g);      a[1] = ldrow8(hi + 32 + 8*g);
    a[2] = ldrow8(hj + 8*g);      a[3] = ldrow8(hj + 32 + 8*g);

    float nr[4], dr[4];
#pragma unroll
    for (int r=0;r<4;r++){ nr[r] = __shfl(nrm, 4*g+r, 64); dr[r] = __shfl(dot, 4*g+r, 64); }

    f32x4 acc[4];
#pragma unroll
    for (int nb=0;nb<4;nb++)
#pragma unroll
      for (int r=0;r<4;r++)
        acc[nb][r] = nr[r]*wn[nb] + dr[r]*wd[nb];
#pragma unroll
    for (int kb=0;kb<4;kb++)
#pragma unroll
      for (int nb=0;nb<4;nb++)
        acc[nb] = __builtin_amdgcn_mfma_f32_16x16x32_bf16(
            a[kb], __builtin_bit_cast(bf16x8, sW[(kb*4+nb)*64 + lane]), acc[nb], 0,0,0);

    float o1[4][4];
#pragma unroll
    for (int nb=0;nb<4;nb++)
#pragma unroll
      for (int r=0;r<4;r++)
        o1[nb][r] = fmaxf(acc[nb][r]*escale[nb] + eshift[nb], 0.f);

    // transpose bounce 1 (D-layout -> A-layout), XOR-swizzled to dodge bank conflicts
    asm volatile("s_waitcnt lgkmcnt(0)" ::: "memory");
#pragma unroll
    for (int nb=0;nb<4;nb++)
#pragma unroll
      for (int r=0;r<4;r++){
        const int mr = 4*g + r;
        tb[mr*64 + ((16*nb + q) ^ ((mr&7)<<3))] = (ushort)f2bf(o1[nb][r]);
      }
    asm volatile("s_waitcnt lgkmcnt(0)" ::: "memory");
    bf16x8 a2[2];
#pragma unroll
    for (int kb=0;kb<2;kb++){
      const int k0 = 32*kb + 8*g;
      uint4 uv = *(const uint4*)(tb + q*64 + (k0 ^ ((q&7)<<3)));
      a2[kb] = __builtin_bit_cast(bf16x8, uv);
    }

    f32x4 acc2[4];
#pragma unroll
    for (int nb=0;nb<4;nb++){ acc2[nb][0]=vbe2[nb]; acc2[nb][1]=vbe2[nb]; acc2[nb][2]=vbe2[nb]; acc2[nb][3]=vbe2[nb]; }
#pragma unroll
    for (int kb=0;kb<2;kb++)
#pragma unroll
      for (int nb=0;nb<4;nb++)
        acc2[nb] = __builtin_amdgcn_mfma_f32_16x16x32_bf16(
            a2[kb], __builtin_bit_cast(bf16x8, sW[1024 + (kb*4+nb)*64 + lane]), acc2[nb], 0,0,0);

    float o2[4][4];
#pragma unroll
    for (int nb=0;nb<4;nb++)
#pragma unroll
      for (int r=0;r<4;r++)
        o2[nb][r] = fmaxf(acc2[nb][r], 0.f);

    float gate[4];
#pragma unroll
    for (int r=0;r<4;r++){
      float s = o2[0][r]*vwm[0] + o2[1][r]*vwm[1] + o2[2][r]*vwm[2] + o2[3][r]*vwm[3];
      s += __shfl_xor(s,1,64); s += __shfl_xor(s,2,64);
      s += __shfl_xor(s,4,64); s += __shfl_xor(s,8,64);
      gate[r] = 1.f/(1.f + __expf(-(s + bmv)));
    }

    float mv[4][4];
#pragma unroll
    for (int nb=0;nb<4;nb++)
#pragma unroll
      for (int r=0;r<4;r++){
        mv[nb][r] = o2[nb][r]*gate[r];
        outm[(size_t)(eb + 4*g + r)*64 + 16*nb + q] = mv[nb][r];
      }

    // transpose bounce 2 (m -> A-layout)
    asm volatile("s_waitcnt lgkmcnt(0)" ::: "memory");
#pragma unroll
    for (int nb=0;nb<4;nb++)
#pragma unroll
      for (int r=0;r<4;r++){
        const int mr = 4*g + r;
        tb[mr*64 + ((16*nb + q) ^ ((mr&7)<<3))] = (ushort)f2bf(mv[nb][r]);
      }
    asm volatile("s_waitcnt lgkmcnt(0)" ::: "memory");
    bf16x8 a3[2];
#pragma unroll
    for (int kb=0;kb<2;kb++){
      const int k0 = 32*kb + 8*g;
      uint4 uv = *(const uint4*)(tb + q*64 + (k0 ^ ((q&7)<<3)));
      a3[kb] = __builtin_bit_cast(bf16x8, uv);
    }

    f32x4 acc3[4];
#pragma unroll
    for (int nb=0;nb<4;nb++){ acc3[nb][0]=vbx1[nb]; acc3[nb][1]=vbx1[nb]; acc3[nb][2]=vbx1[nb]; acc3[nb][3]=vbx1[nb]; }
#pragma unroll
    for (int kb=0;kb<2;kb++)
#pragma unroll
      for (int nb=0;nb<4;nb++)
        acc3[nb] = __builtin_amdgcn_mfma_f32_16x16x32_bf16(
            a3[kb], __builtin_bit_cast(bf16x8, sW[1536 + (kb*4+nb)*64 + lane]), acc3[nb], 0,0,0);

    float pd[4];
#pragma unroll
    for (int r=0;r<4;r++){
      float s = fmaxf(acc3[0][r],0.f)*vwx2[0] + fmaxf(acc3[1][r],0.f)*vwx2[1]
              + fmaxf(acc3[2][r],0.f)*vwx2[2] + fmaxf(acc3[3][r],0.f)*vwx2[3];
      s += __shfl_xor(s,1,64); s += __shfl_xor(s,2,64);
      s += __shfl_xor(s,4,64); s += __shfl_xor(s,8,64);
      pd[r] = s;
    }
    if (q == 0){
#pragma unroll
      for (int r=0;r<4;r++) phx[eb + 4*g + r] = pd[r];
    }
  }
}

// ---------------- per-node aggregation: agg_h and x_new ----------------
// Latency-optimized: SGPR row bounds, 8-wide independent m-row gathers,
// x-part parallelized as (16 edges x 4 comps) per wave iteration.
__global__ __launch_bounds__(256) void k_agg(
    const float* __restrict__ x, const int* __restrict__ ej,
    const int* __restrict__ row, const int* __restrict__ csr,
    const float* __restrict__ m, const float* __restrict__ phx,
    float* __restrict__ aggh, float* __restrict__ out)
{
  const int lane = threadIdx.x & 63, wid = threadIdx.x >> 6;
  const int comp = lane & 3, eoff = lane >> 2;
  const int gw = blockIdx.x*4 + wid, nw = gridDim.x*4;
  for (int v = gw; v < NN; v += nw){
    const int s  = __builtin_amdgcn_readfirstlane(row[v]);
    const int e1 = __builtin_amdgcn_readfirstlane(row[v+1]);

    // ---- m aggregation: all 64 lanes = channels, 8 rows in flight ----
    float ah = 0.f;
    int p = s;
    for (; p + 8 <= e1; p += 8){
      const int c0=csr[p+0], c1=csr[p+1], c2=csr[p+2], c3=csr[p+3];
      const int c4=csr[p+4], c5=csr[p+5], c6=csr[p+6], c7=csr[p+7];
      const float v0 = m[(size_t)c0*64 + lane];
      const float v1 = m[(size_t)c1*64 + lane];
      const float v2 = m[(size_t)c2*64 + lane];
      const float v3 = m[(size_t)c3*64 + lane];
      const float v4 = m[(size_t)c4*64 + lane];
      const float v5 = m[(size_t)c5*64 + lane];
      const float v6 = m[(size_t)c6*64 + lane];
      const float v7 = m[(size_t)c7*64 + lane];
      ah += ((v0+v1)+(v2+v3)) + ((v4+v5)+(v6+v7));
    }
    for (; p < e1; ++p) ah += m[(size_t)csr[p]*64 + lane];
    aggh[(size_t)v*64 + lane] = ah;

    // ---- x aggregation: 16 edges x 4 components per iteration ----
    const float xv = x[4*v + comp];
    float ax = 0.f;
    for (int p2 = s; p2 < e1; p2 += 16){
      const int idx = p2 + eoff;
      if (idx < e1){
        const int e = csr[idx];
        const int j = ej[e];
        float tr = (xv - x[4*j + comp]) * phx[e];
        ax += fminf(fmaxf(tr, -100.f), 100.f);
      }
    }
    ax += __shfl_xor(ax, 4, 64);
    ax += __shfl_xor(ax, 8, 64);
    ax += __shfl_xor(ax,16, 64);
    ax += __shfl_xor(ax,32, 64);
    if (lane < 4){
      const float deg = (float)(e1 - s);
      out[OUT_X + 4*v + lane] = xv + ax / fmaxf(deg, 1.f);
    }
  }
}

// ---------------- node pass 1: y_h = hin@Wh1 (bias dropped: BN absorbs it) + stats ----------------
__global__ __launch_bounds__(256) void k_h1(
    const float* __restrict__ h, const float* __restrict__ aggh, const float* __restrict__ attr,
    const float* __restrict__ Wh1, float* __restrict__ yh, float* __restrict__ wsf)
{
  const int lane = threadIdx.x & 63, wid = threadIdx.x >> 6;
  const int g = lane >> 4, q = lane & 15;

  bf16x8 wf[4][4];
#pragma unroll
  for (int kb=0;kb<4;kb++)
#pragma unroll
    for (int nb=0;nb<4;nb++)
#pragma unroll
      for (int j=0;j<8;j++)
        wf[kb][nb][j] = f2bf(Wh1[(32*kb + 8*g + j)*64 + 16*nb + q]);
  float wa[8][4];
#pragma unroll
  for (int a8=0;a8<8;a8++)
#pragma unroll
    for (int nb=0;nb<4;nb++)
      wa[a8][nb] = Wh1[(128+a8)*64 + 16*nb + q];

  float ssum[4]={0.f,0.f,0.f,0.f}, ssq[4]={0.f,0.f,0.f,0.f};
  const int gw = blockIdx.x*4 + wid, nw = gridDim.x*4;
  for (int t = gw; t < NN/16; t += nw){
    const int rb = t*16;
    bf16x8 a[4];
    const float* hp = h    + (size_t)(rb+q)*64;
    const float* ap = aggh + (size_t)(rb+q)*64;
    a[0]=ldrow8(hp + 8*g); a[1]=ldrow8(hp + 32 + 8*g);
    a[2]=ldrow8(ap + 8*g); a[3]=ldrow8(ap + 32 + 8*g);

    float at[4][8];
#pragma unroll
    for (int r=0;r<4;r++){
      const float* pp = attr + (size_t)(rb + 4*g + r)*8;
      float4 p0 = *(const float4*)pp; float4 p1 = *(const float4*)(pp + 4);
      at[r][0]=p0.x; at[r][1]=p0.y; at[r][2]=p0.z; at[r][3]=p0.w;
      at[r][4]=p1.x; at[r][5]=p1.y; at[r][6]=p1.z; at[r][7]=p1.w;
    }
    f32x4 acc[4];
#pragma unroll
    for (int nb=0;nb<4;nb++)
#pragma unroll
      for (int r=0;r<4;r++){
        float ci = 0.f;
#pragma unroll
        for (int a8=0;a8<8;a8++) ci += at[r][a8]*wa[a8][nb];
        acc[nb][r] = ci;
      }
#pragma unroll
    for (int kb=0;kb<4;kb++)
#pragma unroll
      for (int nb=0;nb<4;nb++)
        acc[nb] = __builtin_amdgcn_mfma_f32_16x16x32_bf16(a[kb], wf[kb][nb], acc[nb], 0,0,0);

#pragma unroll
    for (int nb=0;nb<4;nb++)
#pragma unroll
      for (int r=0;r<4;r++){
        float v = acc[nb][r];
        yh[(size_t)(rb + 4*g + r)*64 + 16*nb + q] = v;
        ssum[nb] += v; ssq[nb] += v*v;
      }
  }
#pragma unroll
  for (int nb=0;nb<4;nb++){
    float s = ssum[nb], z = ssq[nb];
    s += __shfl_xor(s,16,64); s += __shfl_xor(s,32,64);
    z += __shfl_xor(z,16,64); z += __shfl_xor(z,32,64);
    if (lane < 16){
      atomicAdd(wsf + O_HSUM + 16*nb + lane, s);
      atomicAdd(wsf + O_HSQ  + 16*nb + lane, z);
    }
  }
}

// ---------------- node pass 2: h_new = h + relu(BN(y_h))@Wh2 + b_h2 ----------------
__global__ __launch_bounds__(256) void k_h2(
    const float* __restrict__ h, const float* __restrict__ yh,
    const float* __restrict__ Wh2, const float* __restrict__ bh2,
    const float* __restrict__ wsf, float* __restrict__ out)
{
  const int lane = threadIdx.x & 63, wid = threadIdx.x >> 6;
  const int g = lane >> 4, q = lane & 15;

  bf16x8 wf[2][4];
#pragma unroll
  for (int kb=0;kb<2;kb++)
#pragma unroll
    for (int nb=0;nb<4;nb++)
#pragma unroll
      for (int j=0;j<8;j++)
        wf[kb][nb][j] = f2bf(Wh2[(32*kb + 8*g + j)*64 + 16*nb + q]);

  float sc[2][8], sh[2][8];
#pragma unroll
  for (int kb=0;kb<2;kb++)
#pragma unroll
    for (int j=0;j<8;j++){
      const int k = 32*kb + 8*g + j;
      sc[kb][j] = wsf[O_HSC + k]; sh[kb][j] = wsf[O_HSH + k];
    }
  float vb[4];
#pragma unroll
  for (int nb=0;nb<4;nb++) vb[nb] = bh2[16*nb + q];

  const int gw = blockIdx.x*4 + wid, nw = gridDim.x*4;
  for (int t = gw; t < NN/16; t += nw){
    const int rb = t*16;
    const float* yp = yh + (size_t)(rb+q)*64;
    bf16x8 a[2];
#pragma unroll
    for (int kb=0;kb<2;kb++){
      float4 p0 = *(const float4*)(yp + 32*kb + 8*g);
      float4 p1 = *(const float4*)(yp + 32*kb + 8*g + 4);
      float v[8] = {p0.x,p0.y,p0.z,p0.w,p1.x,p1.y,p1.z,p1.w};
#pragma unroll
      for (int j=0;j<8;j++)
        a[kb][j] = f2bf(fmaxf(v[j]*sc[kb][j] + sh[kb][j], 0.f));
    }
    f32x4 acc[4];
#pragma unroll
    for (int nb=0;nb<4;nb++){ acc[nb][0]=vb[nb]; acc[nb][1]=vb[nb]; acc[nb][2]=vb[nb]; acc[nb][3]=vb[nb]; }
#pragma unroll
    for (int kb=0;kb<2;kb++)
#pragma unroll
      for (int nb=0;nb<4;nb++)
        acc[nb] = __builtin_amdgcn_mfma_f32_16x16x32_bf16(a[kb], wf[kb][nb], acc[nb], 0,0,0);

#pragma unroll
    for (int nb=0;nb<4;nb++)
#pragma unroll
      for (int r=0;r<4;r++){
        const size_t idx = (size_t)(rb + 4*g + r)*64 + 16*nb + q;
        out[idx] = h[idx] + acc[nb][r];
      }
  }
}

extern "C" void kernel_launch(void* const* d_in, const int* in_sizes, int n_in,
                              void* d_out, int out_size, void* d_ws, size_t ws_size,
                              hipStream_t stream){
  const float* h    = (const float*)d_in[0];
  const float* x    = (const float*)d_in[1];
  const int*   ei   = (const int*)d_in[2];
  const int*   ej   = (const int*)d_in[3];
  const float* attr = (const float*)d_in[4];
  const float* We1  = (const float*)d_in[5];
  const float* ge   = (const float*)d_in[6];
  const float* be   = (const float*)d_in[7];
  const float* We2  = (const float*)d_in[8];
  const float* be2  = (const float*)d_in[9];
  const float* Wm   = (const float*)d_in[10];
  const float* bm   = (const float*)d_in[11];
  const float* Wx1  = (const float*)d_in[12];
  const float* bx1  = (const float*)d_in[13];
  const float* Wx2  = (const float*)d_in[14];
  const float* Wh1  = (const float*)d_in[15];
  // d_in[16] = b_h1 : absorbed by batchnorm, unused
  const float* gh   = (const float*)d_in[17];
  const float* bh   = (const float*)d_in[18];
  const float* Wh2  = (const float*)d_in[19];
  const float* bh2  = (const float*)d_in[20];

  float* out = (float*)d_out;
  float* wsf = (float*)d_ws;
  int*   wsi = (int*)d_ws;

  hipMemsetAsync(wsf + O_ESUM, 0, 256*sizeof(float), stream);   // all 4 stat blocks
  hipMemsetAsync(wsi + O_CNT, 0, NN*sizeof(int), stream);

  k_e1<<<512,256,0,stream>>>(h, x, ei, ej, We1, wsf, wsi);
  k_stats<<<1,64,0,stream>>>(wsf+O_ESUM, wsf+O_ESQ, ge, be, wsf+O_ESC, wsf+O_ESH, 1.0f/(float)NE);
  k_scan_a<<<49,1024,0,stream>>>(wsi+O_CNT, wsi+O_ROW+1, wsi+O_BSUM, NN);
  k_scan_b<<<1,64,0,stream>>>(wsi+O_BSUM, 49);
  k_scan_c<<<49,1024,0,stream>>>(wsi+O_CNT, wsi+O_ROW, wsi+O_CUR, wsi+O_BSUM, NN);
  k_scatter<<<(NE+255)/256,256,0,stream>>>(ei, wsi+O_CUR, wsi+O_CSR);
  k_e2<<<1024,256,0,stream>>>(h, x, ei, ej, We1, We2, be2, Wm, bm, Wx1, bx1, Wx2,
                              wsf, out + OUT_M, wsf + O_PHX);
  k_agg<<<2048,256,0,stream>>>(x, ej, wsi+O_ROW, wsi+O_CSR, out + OUT_M, wsf + O_PHX,
                               wsf + O_AGGH, out);
  k_h1<<<256,256,0,stream>>>(h, wsf + O_AGGH, attr, Wh1, wsf + O_YH, wsf);
  k_stats<<<1,64,0,stream>>>(wsf+O_HSUM, wsf+O_HSQ, gh, bh, wsf+O_HSC, wsf+O_HSH, 1.0f/(float)NN);
  k_h2<<<256,256,0,stream>>>(h, wsf + O_YH, Wh2, bh2, wsf, out);
}